// Round 3
// baseline (391.517 us; speedup 1.0000x reference)
//
#include <hip/hip_runtime.h>
#include <hip/hip_bf16.h>

#define B_    4
#define N_    8192
#define TOT   (B_*N_)      // 32768 points
#define KNN_  16
#define PPW   8            // points per wave in k2
#define PITCH 68           // LDS tile pitch in halfs: 136B rows (8B-aligned).
                           // quad row offset 4*68 halfs = 136 words == 8 mod 32
                           // -> b16 C-layout writes spread all 32 banks (2-way, free)

typedef _Float16 half8  __attribute__((ext_vector_type(8)));
typedef _Float16 half4  __attribute__((ext_vector_type(4)));
typedef _Float16 half2v __attribute__((ext_vector_type(2)));
typedef float    floatx4 __attribute__((ext_vector_type(4)));

#define MFMA16(A, Bv, C) __builtin_amdgcn_mfma_f32_16x16x32_f16((A), (Bv), (C), 0, 0, 0)

__device__ __forceinline__ void lds_fence(){
  asm volatile("s_waitcnt lgkmcnt(0)" ::: "memory");
}
__device__ __forceinline__ half8 h8_load_f32(const float* __restrict__ p){
  float4 a = *(const float4*)p;
  float4 b = *(const float4*)(p + 4);
  half8 r;
  r[0] = (_Float16)a.x; r[1] = (_Float16)a.y; r[2] = (_Float16)a.z; r[3] = (_Float16)a.w;
  r[4] = (_Float16)b.x; r[5] = (_Float16)b.y; r[6] = (_Float16)b.z; r[7] = (_Float16)b.w;
  return r;
}
__device__ __forceinline__ void store8f(float* __restrict__ p, half8 v){
  float4 a = {(float)v[0], (float)v[1], (float)v[2], (float)v[3]};
  float4 b = {(float)v[4], (float)v[5], (float)v[6], (float)v[7]};
  *(float4*)p = a;
  *(float4*)(p + 4) = b;
}
// read 8 consecutive halfs from an 8B-aligned LDS address as 2x b64 (conflict-free at PITCH=68)
__device__ __forceinline__ half8 tile_read8(const _Float16* t, int idx){
  half4 lo = *(const half4*)(t + idx);
  half4 hi = *(const half4*)(t + idx + 4);
  half8 r;
  #pragma unroll
  for (int j = 0; j < 4; j++){ r[j] = lo[j]; r[4+j] = hi[j]; }
  return r;
}
// B-fragment of a 64x64 row-major f32 weight, loaded directly from global.
// frag (kt,nt): lane holds W[kt*32 + quad*8 + j][nt*16 + m16], j=0..7
__device__ __forceinline__ half8 wfrag(const float* __restrict__ W, int kb, int n){
  half8 v;
  #pragma unroll
  for (int j = 0; j < 8; j++) v[j] = (_Float16)W[(kb + j)*64 + n];
  return v;
}
// packed-f16 sum-reduction over the 16 lanes of each quad group (masks 1,2,4,8)
__device__ __forceinline__ half8 red_over_m16(half8 x){
  union { half8 h; int i[4]; } u; u.h = x;
  #pragma unroll
  for (int mask = 1; mask < 16; mask <<= 1){
    #pragma unroll
    for (int t = 0; t < 4; t++){
      int o = __shfl_xor(u.i[t], mask);
      union { int i; half2v h; } a, b;
      a.i = u.i[t]; b.i = o;
      a.h = a.h + b.h;
      u.i[t] = a.i;
    }
  }
  return u.h;
}

// LDS B-fragment staging for k1 (once per block; k1 is not the hot kernel)
__device__ void fill_w64(half8* dst, const float* __restrict__ W, int tid){
  for (int i = tid; i < 512; i += 256){
    int lane = i & 63, nt = (i >> 6) & 3, kt = i >> 8;
    int n  = nt*16 + (lane & 15);
    int kb = kt*32 + ((lane >> 4) & 3)*8;
    half8 v;
    #pragma unroll
    for (int j = 0; j < 8; j++) v[j] = (_Float16)W[(kb + j)*64 + n];
    dst[i] = v;
  }
}

// ---------------- kernel 1: x = fc1(features); q/xk/xv = x @ {wq,wk,wv} ----------------
__global__ __launch_bounds__(256, 2) void k1_qkv(
    const float* __restrict__ feat, const float* __restrict__ fc1w, const float* __restrict__ fc1b,
    const float* __restrict__ wqw, const float* __restrict__ wkw, const float* __restrict__ wvw,
    _Float16* __restrict__ qws, _Float16* __restrict__ kws, _Float16* __restrict__ vws)
{
  __shared__ half8 Sfc1[512], Sq[512], Sk[512], Sv[512];
  __shared__ alignas(16) _Float16 xt[4][16*PITCH];
  const int tid = threadIdx.x;
  fill_w64(Sfc1, fc1w, tid);
  fill_w64(Sq, wqw, tid);
  fill_w64(Sk, wkw, tid);
  fill_w64(Sv, wvw, tid);
  __syncthreads();

  const int wave = tid >> 6, lane = tid & 63, quad = lane >> 4, m16 = lane & 15;
  _Float16* tx = &xt[wave][0];
  const int rowbase = blockIdx.x*64 + wave*16;
  float fb[4];
  #pragma unroll
  for (int nt = 0; nt < 4; nt++) fb[nt] = fc1b[nt*16 + m16];

  const int arow = rowbase + m16;
  half8 Fa0 = h8_load_f32(&feat[arow*64 + quad*8]);
  half8 Fa1 = h8_load_f32(&feat[arow*64 + 32 + quad*8]);
  const floatx4 z4 = {0.f, 0.f, 0.f, 0.f};

  #pragma unroll
  for (int nt = 0; nt < 4; nt++){
    floatx4 acc = MFMA16(Fa0, Sfc1[nt*64 + lane], z4);
    acc = MFMA16(Fa1, Sfc1[(4 + nt)*64 + lane], acc);
    const int col = nt*16 + m16;
    #pragma unroll
    for (int r = 0; r < 4; r++)
      tx[(quad*4 + r)*PITCH + col] = (_Float16)(acc[r] + fb[nt]);
  }
  lds_fence();
  const half8 Ax0 = tile_read8(tx, m16*PITCH + quad*8);
  const half8 Ax1 = tile_read8(tx, m16*PITCH + 32 + quad*8);

#define EMIT_QKV(S, OUT)                                                      \
  { _Pragma("unroll")                                                         \
    for (int nt = 0; nt < 4; nt++){                                           \
      floatx4 acc = MFMA16(Ax0, S[nt*64 + lane], z4);                         \
      acc = MFMA16(Ax1, S[(4 + nt)*64 + lane], acc);                          \
      _Pragma("unroll")                                                       \
      for (int r = 0; r < 4; r++)                                             \
        OUT[(rowbase + quad*4 + r)*64 + nt*16 + m16] = (_Float16)acc[r];      \
    } }
  EMIT_QKV(Sq, qws)
  EMIT_QKV(Sk, kws)
  EMIT_QKV(Sv, vws)
#undef EMIT_QKV
}

// ---------------- kernel 2: per-point fused pos_enc / attention ----------------
__global__ __launch_bounds__(256, 3) void k2_point(
    const float* __restrict__ xyz, const int* __restrict__ knn,
    const float* __restrict__ d1w, const float* __restrict__ d1b,
    const float* __restrict__ d2w, const float* __restrict__ d2b,
    const float* __restrict__ g1w, const float* __restrict__ g1b,
    const float* __restrict__ g2w, const float* __restrict__ g2b,
    const _Float16* __restrict__ qws, const _Float16* __restrict__ kws,
    const _Float16* __restrict__ vws,
    _Float16* __restrict__ r0, float* __restrict__ attn_out)
{
  __shared__ alignas(16) _Float16 tiles[4][16*PITCH];   // one 16x68 tile per wave (~8.7KB total)
  const int tid = threadIdx.x;
  const int wave = tid >> 6, lane = tid & 63, quad = lane >> 4, m16 = lane & 15;
  _Float16* tA = &tiles[wave][0];

  // weight B-fragments direct from global into registers (AGPR-parked by compiler)
  half8 Fd1[4], Fd2[2][4], Fg1[2][4], Fg2[2][4];
  #pragma unroll
  for (int nt = 0; nt < 4; nt++){
    const int n = nt*16 + m16;
    // d1 is (3,64): pad K to 32 with zeros
    {
      half8 v;
      #pragma unroll
      for (int j = 0; j < 8; j++){
        int k = quad*8 + j;
        v[j] = (k < 3) ? (_Float16)d1w[k*64 + n] : (_Float16)0.0f;
      }
      Fd1[nt] = v;
    }
    #pragma unroll
    for (int kt = 0; kt < 2; kt++){
      const int kb = kt*32 + quad*8;
      Fd2[kt][nt] = wfrag(d2w, kb, n);
      Fg1[kt][nt] = wfrag(g1w, kb, n);
      Fg2[kt][nt] = wfrag(g2w, kb, n);
    }
  }
  float bd1[4], bd2[4], bg1[4], bg2[4];
  #pragma unroll
  for (int nt = 0; nt < 4; nt++){
    const int c = nt*16 + m16;
    bd1[nt] = d1b[c]; bd2[nt] = d2b[c];
    bg1[nt] = g1b[c]; bg2[nt] = g2b[c];
  }
  const floatx4 z4 = {0.f, 0.f, 0.f, 0.f};
  const float SC = 0.18033688f;   // (1/sqrt(64)) * log2(e)

  const int base = blockIdx.x*(4*PPW) + wave*PPW;
  const int bb   = (base >> 13) << 13;          // batch row base (N=8192)

  // preload all neighbor indices for this wave's 8 points
  int idxs[PPW];
  #pragma unroll
  for (int p = 0; p < PPW; p++) idxs[p] = knn[(base + p)*KNN_ + m16];

  #pragma unroll
  for (int p = 0; p < PPW; p++){
    const int gpt  = base + p;
    const int grow = bb + idxs[p];

    // ---- issue all global loads for this point up front ----
    const half8 Ka0 = *(const half8*)&kws[grow*64 + quad*8];
    const half8 Ka1 = *(const half8*)&kws[grow*64 + 32 + quad*8];
    const half8 Va0 = *(const half8*)&vws[grow*64 + quad*8];
    const half8 Va1 = *(const half8*)&vws[grow*64 + 32 + quad*8];
    const half8 Qa0 = *(const half8*)&qws[gpt*64 + quad*8];
    const half8 Qa1 = *(const half8*)&qws[gpt*64 + 32 + quad*8];
    float rel[3];
    #pragma unroll
    for (int j = 0; j < 3; j++) rel[j] = xyz[gpt*3 + j] - xyz[grow*3 + j];

    // relative position A-operand (only quad 0, k<3 nonzero)
    half8 Ar;
    #pragma unroll
    for (int j = 0; j < 8; j++) Ar[j] = (_Float16)0.0f;
    if (quad == 0){
      #pragma unroll
      for (int j = 0; j < 3; j++) Ar[j] = (_Float16)rel[j];
    }

    // stage 1: t = relu(rel @ d1 + b)  -> tile
    #pragma unroll
    for (int nt = 0; nt < 4; nt++){
      floatx4 acc = MFMA16(Ar, Fd1[nt], z4);
      const int col = nt*16 + m16;
      #pragma unroll
      for (int r = 0; r < 4; r++){
        float t = acc[r] + bd1[nt];
        tA[(quad*4 + r)*PITCH + col] = (_Float16)(t > 0.f ? t : 0.f);
      }
    }
    lds_fence();
    const half8 At0 = tile_read8(tA, m16*PITCH + quad*8);
    const half8 At1 = tile_read8(tA, m16*PITCH + 32 + quad*8);

    // stage 2: P = t @ d2 + b  -> tile (write-after-read safe: DS pipe in-order per wave)
    #pragma unroll
    for (int nt = 0; nt < 4; nt++){
      floatx4 acc = MFMA16(At0, Fd2[0][nt], z4);
      acc = MFMA16(At1, Fd2[1][nt], acc);
      const int col = nt*16 + m16;
      #pragma unroll
      for (int r = 0; r < 4; r++)
        tA[(quad*4 + r)*PITCH + col] = (_Float16)(acc[r] + bd2[nt]);
    }
    lds_fence();
    const half8 Pa0 = tile_read8(tA, m16*PITCH + quad*8);
    const half8 Pa1 = tile_read8(tA, m16*PITCH + 32 + quad*8);

    // H = q - k + P
    const half8 H0 = Qa0 - Ka0 + Pa0;
    const half8 H1 = Qa1 - Ka1 + Pa1;

    // stage 3: u = relu(H @ g1 + b)  -> tile
    #pragma unroll
    for (int nt = 0; nt < 4; nt++){
      floatx4 acc = MFMA16(H0, Fg1[0][nt], z4);
      acc = MFMA16(H1, Fg1[1][nt], acc);
      const int col = nt*16 + m16;
      #pragma unroll
      for (int r = 0; r < 4; r++){
        float t = acc[r] + bg1[nt];
        tA[(quad*4 + r)*PITCH + col] = (_Float16)(t > 0.f ? t : 0.f);
      }
    }
    lds_fence();
    const half8 U0 = tile_read8(tA, m16*PITCH + quad*8);
    const half8 U1 = tile_read8(tA, m16*PITCH + 32 + quad*8);

    // stage 4: logits = u @ g2 + b (C layout)
    float A2[4][4];
    #pragma unroll
    for (int nt = 0; nt < 4; nt++){
      floatx4 acc = MFMA16(U0, Fg2[0][nt], z4);
      acc = MFMA16(U1, Fg2[1][nt], acc);
      #pragma unroll
      for (int r = 0; r < 4; r++) A2[nt][r] = acc[r] + bg2[nt];
    }

    // softmax over the 16 neighbors (rows): local 4 + cross-quad shfl(16,32)
    #pragma unroll
    for (int nt = 0; nt < 4; nt++){
      float mx = fmaxf(fmaxf(A2[nt][0], A2[nt][1]), fmaxf(A2[nt][2], A2[nt][3]));
      mx = fmaxf(mx, __shfl_xor(mx, 16));
      mx = fmaxf(mx, __shfl_xor(mx, 32));
      float s = 0.f;
      #pragma unroll
      for (int r = 0; r < 4; r++){
        float e = exp2f((A2[nt][r] - mx)*SC);
        A2[nt][r] = e; s += e;
      }
      s += __shfl_xor(s, 16);
      s += __shfl_xor(s, 32);
      const float inv = 1.0f / s;
      const int col = nt*16 + m16;
      #pragma unroll
      for (int r = 0; r < 4; r++)
        tA[(quad*4 + r)*PITCH + col] = (_Float16)(A2[nt][r]*inv);
    }
    lds_fence();
    const half8 Aa0 = tile_read8(tA, m16*PITCH + quad*8);
    const half8 Aa1 = tile_read8(tA, m16*PITCH + 32 + quad*8);

    // attn output (f32), A-layout contiguous stores
    float* ap = attn_out + ((size_t)gpt*KNN_ + m16)*64;
    store8f(ap + quad*8, Aa0);
    store8f(ap + 32 + quad*8, Aa1);

    // res0 = sum_n attn * (v + pos_enc); packed-f16 reduction over the 16 m-lanes
    const half8 W0 = Aa0 * (Va0 + Pa0);
    const half8 W1 = Aa1 * (Va1 + Pa1);
    const half8 R0 = red_over_m16(W0);
    const half8 R1 = red_over_m16(W1);
    if (m16 == 0){
      *(half8*)&r0[gpt*64 + quad*8] = R0;
      *(half8*)&r0[gpt*64 + 32 + quad*8] = R1;
    }
  }
}

// ---------------- kernel 3: res = res0 @ fc2 + fc2_b + features (LDS-free) ----------------
__global__ __launch_bounds__(256, 4) void k3_fc2(
    const _Float16* __restrict__ r0, const float* __restrict__ fc2w,
    const float* __restrict__ fc2b, const float* __restrict__ feat,
    float* __restrict__ out_res)
{
  const int tid = threadIdx.x;
  const int wave = tid >> 6, lane = tid & 63, quad = lane >> 4, m16 = lane & 15;
  const int rowbase = blockIdx.x*64 + wave*16;

  half8 S[2][4];
  #pragma unroll
  for (int kt = 0; kt < 2; kt++)
    #pragma unroll
    for (int nt = 0; nt < 4; nt++)
      S[kt][nt] = wfrag(fc2w, kt*32 + quad*8, nt*16 + m16);

  float fb[4];
  #pragma unroll
  for (int nt = 0; nt < 4; nt++) fb[nt] = fc2b[nt*16 + m16];

  const half8 A0 = *(const half8*)&r0[(rowbase + m16)*64 + quad*8];
  const half8 A1 = *(const half8*)&r0[(rowbase + m16)*64 + 32 + quad*8];
  const floatx4 z4 = {0.f, 0.f, 0.f, 0.f};

  #pragma unroll
  for (int nt = 0; nt < 4; nt++){
    floatx4 acc = MFMA16(A0, S[0][nt], z4);
    acc = MFMA16(A1, S[1][nt], acc);
    #pragma unroll
    for (int r = 0; r < 4; r++){
      const int rowg = rowbase + quad*4 + r;
      const int col  = nt*16 + m16;
      out_res[rowg*64 + col] = acc[r] + fb[nt] + feat[rowg*64 + col];
    }
  }
}

extern "C" void kernel_launch(void* const* d_in, const int* in_sizes, int n_in,
                              void* d_out, int out_size, void* d_ws, size_t ws_size,
                              hipStream_t stream)
{
  (void)in_sizes; (void)n_in; (void)out_size; (void)ws_size;
  const float* xyz  = (const float*)d_in[0];
  const float* feat = (const float*)d_in[1];
  const int*   knn  = (const int*)d_in[2];
  const float* fc1w = (const float*)d_in[3];
  const float* fc1b = (const float*)d_in[4];
  const float* fc2w = (const float*)d_in[5];
  const float* fc2b = (const float*)d_in[6];
  const float* d1w  = (const float*)d_in[7];
  const float* d1b  = (const float*)d_in[8];
  const float* d2w  = (const float*)d_in[9];
  const float* d2b  = (const float*)d_in[10];
  const float* g1w  = (const float*)d_in[11];
  const float* g1b  = (const float*)d_in[12];
  const float* g2w  = (const float*)d_in[13];
  const float* g2b  = (const float*)d_in[14];
  const float* wq   = (const float*)d_in[15];
  const float* wk   = (const float*)d_in[16];
  const float* wv   = (const float*)d_in[17];

  _Float16* ws  = (_Float16*)d_ws;
  _Float16* qws = ws;                      // TOT*64 halfs
  _Float16* kws = ws + (size_t)TOT*64;
  _Float16* vws = ws + (size_t)2*TOT*64;
  _Float16* r0  = ws + (size_t)3*TOT*64;

  float* out      = (float*)d_out;
  float* out_res  = out;                     // (B,N,64)
  float* out_attn = out + (size_t)TOT*64;    // (B,N,K,64)

  k1_qkv<<<TOT/64, 256, 0, stream>>>(feat, fc1w, fc1b, wq, wk, wv, qws, kws, vws);
  k2_point<<<TOT/(4*PPW), 256, 0, stream>>>(xyz, knn, d1w, d1b, d2w, d2b,
                                            g1w, g1b, g2w, g2b,
                                            qws, kws, vws, r0, out_attn);
  k3_fc2<<<TOT/64, 256, 0, stream>>>(r0, fc2w, fc2b, feat, out_res);
}